// Round 3
// baseline (287.182 us; speedup 1.0000x reference)
//
#include <hip/hip_runtime.h>

#define OUT_F 11008
#define IN_F  4096
#define NBATCH 8
#define ROWS_PER_BLOCK 4
#define BLOCK 256
// columns processed per thread per k-iter = 4 (int4 of indices, float4 of x)
// k iterations = IN_F / (4*BLOCK) = 4

__global__ __launch_bounds__(BLOCK) void pal_linear_kernel(
    const float* __restrict__ x,        // [8, 4096]
    const int*   __restrict__ widx,     // [11008*4096] values in [0,16)
    const float* __restrict__ lut,      // [352256, 16] (fp16 in ref, uploaded as f32)
    const float* __restrict__ bias,     // [11008]
    float* __restrict__ out)            // [8, 11008]
{
    const int tid = threadIdx.x;
    const int o0  = blockIdx.x * ROWS_PER_BLOCK;

    float acc[ROWS_PER_BLOCK][NBATCH];
#pragma unroll
    for (int r = 0; r < ROWS_PER_BLOCK; ++r)
#pragma unroll
        for (int m = 0; m < NBATCH; ++m) acc[r][m] = 0.0f;

#pragma unroll
    for (int k = 0; k < IN_F / (4 * BLOCK); ++k) {
        const int c = (tid + BLOCK * k) * 4;   // coalesced: lane i -> 16B chunk i

        float4 xv[NBATCH];
#pragma unroll
        for (int m = 0; m < NBATCH; ++m)
            xv[m] = *reinterpret_cast<const float4*>(&x[m * IN_F + c]);

#pragma unroll
        for (int r = 0; r < ROWS_PER_BLOCK; ++r) {
            const int row = o0 + r;
            const int4 idx =
                *reinterpret_cast<const int4*>(&widx[(size_t)row * IN_F + c]);
            // group = row*32 + c/128, uniform across the 4-aligned chunk
            const int gbase = (row * (IN_F / 128) + (c >> 7)) * 16;
            const float w0 = lut[gbase + idx.x];
            const float w1 = lut[gbase + idx.y];
            const float w2 = lut[gbase + idx.z];
            const float w3 = lut[gbase + idx.w];
#pragma unroll
            for (int m = 0; m < NBATCH; ++m) {
                float a = acc[r][m];
                a = fmaf(w0, xv[m].x, a);
                a = fmaf(w1, xv[m].y, a);
                a = fmaf(w2, xv[m].z, a);
                a = fmaf(w3, xv[m].w, a);
                acc[r][m] = a;
            }
        }
    }

    // --- reduction: 32 partial sums per thread, summed over 256 threads ---
    // 1) butterfly within each 64-lane wave
#pragma unroll
    for (int r = 0; r < ROWS_PER_BLOCK; ++r)
#pragma unroll
        for (int m = 0; m < NBATCH; ++m) {
            float v = acc[r][m];
#pragma unroll
            for (int off = 32; off >= 1; off >>= 1)
                v += __shfl_xor(v, off, 64);
            acc[r][m] = v;
        }

    // 2) cross-wave via LDS
    __shared__ float red[BLOCK / 64][ROWS_PER_BLOCK * NBATCH];
    const int wave = tid >> 6;
    const int lane = tid & 63;
    if (lane == 0) {
#pragma unroll
        for (int r = 0; r < ROWS_PER_BLOCK; ++r)
#pragma unroll
            for (int m = 0; m < NBATCH; ++m)
                red[wave][r * NBATCH + m] = acc[r][m];
    }
    __syncthreads();

    if (tid < ROWS_PER_BLOCK * NBATCH) {
        const int r = tid >> 3;   // tid / NBATCH
        const int m = tid & 7;    // tid % NBATCH
        float total = red[0][tid] + red[1][tid] + red[2][tid] + red[3][tid];
        out[(size_t)m * OUT_F + (o0 + r)] = total + bias[o0 + r];
    }
}

extern "C" void kernel_launch(void* const* d_in, const int* in_sizes, int n_in,
                              void* d_out, int out_size, void* d_ws, size_t ws_size,
                              hipStream_t stream) {
    const float* x    = (const float*)d_in[0];
    const int*   widx = (const int*)d_in[1];
    const float* lut  = (const float*)d_in[2];
    const float* bias = (const float*)d_in[3];
    float* out = (float*)d_out;

    pal_linear_kernel<<<OUT_F / ROWS_PER_BLOCK, BLOCK, 0, stream>>>(
        x, widx, lut, bias, out);
}

// Round 4
// 277.506 us; speedup vs baseline: 1.0349x; 1.0349x over previous
//
#include <hip/hip_runtime.h>

#define OUT_F 11008
#define IN_F  4096
#define NBATCH 8
#define R 4                     // output rows per block
#define BLOCK 256
#define NGR 32                  // groups per row = IN_F/128
#define KITERS (IN_F / (4 * BLOCK))   // 4: each thread covers 4 columns per k-iter

__global__ __launch_bounds__(BLOCK, 4) void pal_linear_kernel(
    const float* __restrict__ x,        // [8, 4096]
    const int*   __restrict__ widx,     // [11008*4096] in [0,16)
    const float* __restrict__ lut,      // [352256, 16] f32 on device
    const float* __restrict__ bias,     // [11008]
    float* __restrict__ out)            // [8, 11008]
{
    __shared__ float lutS[R * NGR * 16];            // 8 KB, contiguous slice
    __shared__ float red[BLOCK / 64][R * NBATCH];   // cross-wave reduce

    const int tid = threadIdx.x;
    const int o0  = blockIdx.x * R;

    // ---- stage this block's LUT slice (contiguous 2048 floats) into LDS ----
    {
        const float4* src = reinterpret_cast<const float4*>(lut + (size_t)o0 * NGR * 16);
        float4* dst = reinterpret_cast<float4*>(lutS);
#pragma unroll
        for (int i = 0; i < (R * NGR * 16 / 4) / BLOCK; ++i)   // 2 iters
            dst[tid + i * BLOCK] = src[tid + i * BLOCK];
    }
    __syncthreads();

    float acc[R][NBATCH];
#pragma unroll
    for (int r = 0; r < R; ++r)
#pragma unroll
        for (int m = 0; m < NBATCH; ++m) acc[r][m] = 0.0f;

    // ---- software-pipelined index stream (the 180 MB that sets the floor) ----
    int4 idx_cur[R], idx_nxt[R];
#pragma unroll
    for (int r = 0; r < R; ++r)
        idx_cur[r] = *reinterpret_cast<const int4*>(widx + (size_t)(o0 + r) * IN_F + 4 * tid);

#pragma unroll 1
    for (int k = 0; k < KITERS; ++k) {
        const int c = 4 * (tid + BLOCK * k);

        if (k + 1 < KITERS) {
#pragma unroll
            for (int r = 0; r < R; ++r)
                idx_nxt[r] = *reinterpret_cast<const int4*>(
                    widx + (size_t)(o0 + r) * IN_F + c + 4 * BLOCK);
        }

        // gather all 16 weights from LDS first (short latency, off VMEM pipe)
        const int gcol = (c >> 7) * 16;    // group-within-row * 16
        float w[R][4];
#pragma unroll
        for (int r = 0; r < R; ++r) {
            const float* lr = lutS + r * (NGR * 16) + gcol;
            w[r][0] = lr[idx_cur[r].x];
            w[r][1] = lr[idx_cur[r].y];
            w[r][2] = lr[idx_cur[r].z];
            w[r][3] = lr[idx_cur[r].w];
        }

        // then stream x (L2-hot) one float4 at a time; short live range
#pragma unroll
        for (int m = 0; m < NBATCH; ++m) {
            const float4 xm = *reinterpret_cast<const float4*>(x + m * IN_F + c);
#pragma unroll
            for (int r = 0; r < R; ++r) {
                float a = acc[r][m];
                a = fmaf(w[r][0], xm.x, a);
                a = fmaf(w[r][1], xm.y, a);
                a = fmaf(w[r][2], xm.z, a);
                a = fmaf(w[r][3], xm.w, a);
                acc[r][m] = a;
            }
        }

#pragma unroll
        for (int r = 0; r < R; ++r) idx_cur[r] = idx_nxt[r];
    }

    // ---- reduce 256 threads' partials ----
#pragma unroll
    for (int r = 0; r < R; ++r)
#pragma unroll
        for (int m = 0; m < NBATCH; ++m) {
            float v = acc[r][m];
#pragma unroll
            for (int off = 32; off >= 1; off >>= 1)
                v += __shfl_xor(v, off, 64);
            acc[r][m] = v;
        }

    const int wave = tid >> 6;
    const int lane = tid & 63;
    if (lane == 0) {
#pragma unroll
        for (int r = 0; r < R; ++r)
#pragma unroll
            for (int m = 0; m < NBATCH; ++m)
                red[wave][r * NBATCH + m] = acc[r][m];
    }
    __syncthreads();

    if (tid < R * NBATCH) {
        const int r = tid >> 3;
        const int m = tid & 7;
        float total = red[0][tid] + red[1][tid] + red[2][tid] + red[3][tid];
        out[(size_t)m * OUT_F + (o0 + r)] = total + bias[o0 + r];
    }
}

extern "C" void kernel_launch(void* const* d_in, const int* in_sizes, int n_in,
                              void* d_out, int out_size, void* d_ws, size_t ws_size,
                              hipStream_t stream) {
    const float* x    = (const float*)d_in[0];
    const int*   widx = (const int*)d_in[1];
    const float* lut  = (const float*)d_in[2];
    const float* bias = (const float*)d_in[3];
    float* out = (float*)d_out;

    pal_linear_kernel<<<OUT_F / R, BLOCK, 0, stream>>>(x, widx, lut, bias, out);
}